// Round 1
// baseline (566.851 us; speedup 1.0000x reference)
//
#include <hip/hip_runtime.h>
#include <hip/hip_bf16.h>
#include <stdint.h>
#include <math.h>

#define D_MODEL 1024
#define NUM_HEADS 16
#define D_K 64
#define SEQ 2048
#define BATCH 2
#define SIM_THRESH 0.7f

#define TS 64   // block tile
#define KC 16   // K chunk

// ---------------- Kernel 1: inverse row norms ----------------
// one wave (64 lanes) per row
__global__ void k_inv_norm(const float* __restrict__ x, float* __restrict__ inv_norm, int nrows) {
    int wave = (blockIdx.x * blockDim.x + threadIdx.x) >> 6;
    int lane = threadIdx.x & 63;
    if (wave >= nrows) return;
    const float* row = x + (size_t)wave * D_MODEL;
    float ss = 0.f;
    #pragma unroll
    for (int i = 0; i < D_MODEL / 64; ++i) {
        float a = row[lane + i * 64];
        ss += a * a;
    }
    for (int off = 32; off > 0; off >>= 1) ss += __shfl_down(ss, off, 64);
    if (lane == 0) {
        float n = sqrtf(ss);
        inv_norm[wave] = 1.0f / fmaxf(n, 1e-12f);
    }
}

// ---------------- Kernel 2: V projection  C[m,n] = sum_k A[m,k]*B[n,k] + bias[n] ----------------
__global__ __launch_bounds__(256) void k_gemm_nt_bias(
    const float* __restrict__ A, const float* __restrict__ B,
    const float* __restrict__ bias, float* __restrict__ C,
    int M, int N, int K)
{
    __shared__ float As[KC][TS + 1];   // +1 pad: store pattern k-fast would otherwise 16-way conflict
    __shared__ float Bs[KC][TS + 1];
    int tid = threadIdx.x;
    int tx = tid & 15, ty = tid >> 4;
    int rowBase = blockIdx.y * TS;
    int colBase = blockIdx.x * TS;
    float acc[4][4] = {};
    for (int kk = 0; kk < K; kk += KC) {
        #pragma unroll
        for (int l = 0; l < 4; ++l) {
            int idx = l * 256 + tid;
            int m = idx >> 4;       // 0..63
            int k = idx & 15;       // 0..15
            As[k][m] = A[(size_t)(rowBase + m) * K + kk + k];
            Bs[k][m] = B[(size_t)(colBase + m) * K + kk + k];
        }
        __syncthreads();
        #pragma unroll
        for (int k = 0; k < KC; ++k) {
            float a[4], b[4];
            #pragma unroll
            for (int i = 0; i < 4; ++i) a[i] = As[k][ty + i * 16];
            #pragma unroll
            for (int j = 0; j < 4; ++j) b[j] = Bs[k][tx + j * 16];
            #pragma unroll
            for (int i = 0; i < 4; ++i)
                #pragma unroll
                for (int j = 0; j < 4; ++j)
                    acc[i][j] += a[i] * b[j];
        }
        __syncthreads();
    }
    #pragma unroll
    for (int i = 0; i < 4; ++i) {
        int r = rowBase + ty + i * 16;
        #pragma unroll
        for (int j = 0; j < 4; ++j) {
            int c = colBase + tx + j * 16;
            C[(size_t)r * N + c] = acc[i][j] + bias[c];
        }
    }
}

// ---------------- Kernel 3: sim GEMM + threshold -> mask bytes ----------------
__global__ __launch_bounds__(256) void k_sim_mask(
    const float* __restrict__ x, const float* __restrict__ invn,
    uint8_t* __restrict__ mask)
{
    __shared__ float As[KC][TS + 1];
    __shared__ float Bs[KC][TS + 1];
    int b = blockIdx.z;
    const float* A = x + (size_t)b * SEQ * D_MODEL;
    int tid = threadIdx.x;
    int tx = tid & 15, ty = tid >> 4;
    int rowBase = blockIdx.y * TS;
    int colBase = blockIdx.x * TS;
    float acc[4][4] = {};
    for (int kk = 0; kk < D_MODEL; kk += KC) {
        #pragma unroll
        for (int l = 0; l < 4; ++l) {
            int idx = l * 256 + tid;
            int m = idx >> 4;
            int k = idx & 15;
            As[k][m] = A[(size_t)(rowBase + m) * D_MODEL + kk + k];
            Bs[k][m] = A[(size_t)(colBase + m) * D_MODEL + kk + k];
        }
        __syncthreads();
        #pragma unroll
        for (int k = 0; k < KC; ++k) {
            float a[4], bb[4];
            #pragma unroll
            for (int i = 0; i < 4; ++i) a[i] = As[k][ty + i * 16];
            #pragma unroll
            for (int j = 0; j < 4; ++j) bb[j] = Bs[k][tx + j * 16];
            #pragma unroll
            for (int i = 0; i < 4; ++i)
                #pragma unroll
                for (int j = 0; j < 4; ++j)
                    acc[i][j] += a[i] * bb[j];
        }
        __syncthreads();
    }
    const float* inb = invn + b * SEQ;
    #pragma unroll
    for (int i = 0; i < 4; ++i) {
        int r = rowBase + ty + i * 16;
        float ir = inb[r];
        #pragma unroll
        for (int j = 0; j < 4; ++j) {
            int c = colBase + tx + j * 16;
            float s = acc[i][j] * ir * inb[c];
            mask[((size_t)b * SEQ + r) * SEQ + c] = (s > SIM_THRESH) ? (uint8_t)1 : (uint8_t)0;
        }
    }
}

// ---------------- Kernel 4: mask-driven attention ----------------
// One block per (b, s). If the mask row has exactly one entry t0, softmax over a
// single finite score is exactly 1 => out = v[t0] (no q/k needed). Otherwise run
// the full online-softmax path (computes q/k rows on the fly).
__global__ __launch_bounds__(256) void k_attention(
    const float* __restrict__ x,
    const float* __restrict__ Wq, const float* __restrict__ bq,
    const float* __restrict__ Wk, const float* __restrict__ bk,
    const float* __restrict__ v, const uint8_t* __restrict__ mask,
    float* __restrict__ out)
{
    int s = blockIdx.x;
    int b = blockIdx.y;
    int tid = threadIdx.x;
    const uint8_t* mrow = mask + ((size_t)b * SEQ + s) * SEQ;

    __shared__ int cnt_sh[256];
    __shared__ int idx_sh[256];
    int cnt = 0, last = -1;
    for (int t = tid; t < SEQ; t += 256) {
        if (mrow[t]) { cnt++; last = t; }
    }
    cnt_sh[tid] = cnt;
    idx_sh[tid] = last;
    __syncthreads();
    __shared__ int total_sh, t0_sh;
    if (tid == 0) {
        int total = 0, t0 = -1;
        for (int i = 0; i < 256; ++i) {
            total += cnt_sh[i];
            if (idx_sh[i] >= 0) t0 = idx_sh[i];
        }
        total_sh = total;
        t0_sh = t0;
    }
    __syncthreads();
    int total = total_sh;

    if (total == 1) {
        // singleton row: attention weight is exactly 1 at t0
        int t0 = t0_sh;
        const float* vrow = v + ((size_t)b * SEQ + t0) * D_MODEL;
        int c = tid * 4;                       // 0..1023, float4 chunks
        float4 val = *(const float4*)(vrow + c);
        int h = c >> 6, j = c & 63;
        float* op = out + (((size_t)(b * NUM_HEADS + h) * SEQ + s) * D_K + j);
        *(float4*)op = val;
        return;
    }

    // ---------- general path (correct fallback; expected cold) ----------
    __shared__ float q_row[D_MODEL];
    __shared__ float k_row[D_MODEL];
    __shared__ float accO[D_MODEL];
    __shared__ float m_h[NUM_HEADS], l_h[NUM_HEADS], alpha_h[NUM_HEADS], p_h[NUM_HEADS];

    const float* xrow = x + ((size_t)b * SEQ + s) * D_MODEL;
    for (int c = tid; c < D_MODEL; c += 256) {
        const float* w = Wq + (size_t)c * D_MODEL;
        float acc = bq[c];
        for (int d = 0; d < D_MODEL; ++d) acc += xrow[d] * w[d];
        q_row[c] = acc;
        accO[c] = 0.f;
    }
    if (tid < NUM_HEADS) { m_h[tid] = -INFINITY; l_h[tid] = 0.f; }
    __syncthreads();

    for (int t = 0; t < SEQ; ++t) {
        if (!mrow[t]) continue;
        const float* xt = x + ((size_t)b * SEQ + t) * D_MODEL;
        for (int c = tid; c < D_MODEL; c += 256) {
            const float* w = Wk + (size_t)c * D_MODEL;
            float acc = bk[c];
            for (int d = 0; d < D_MODEL; ++d) acc += xt[d] * w[d];
            k_row[c] = acc;
        }
        __syncthreads();
        if (tid < NUM_HEADS) {
            float sc = 0.f;
            for (int j = 0; j < D_K; ++j) sc += q_row[tid * D_K + j] * k_row[tid * D_K + j];
            sc *= 0.125f;  // 1/sqrt(64)
            float mnew = fmaxf(m_h[tid], sc);
            float alpha = expf(m_h[tid] - mnew);   // exp(-inf)=0 on first hit
            float p = expf(sc - mnew);
            l_h[tid] = l_h[tid] * alpha + p;
            m_h[tid] = mnew;
            alpha_h[tid] = alpha;
            p_h[tid] = p;
        }
        __syncthreads();
        const float* vt = v + ((size_t)b * SEQ + t) * D_MODEL;
        for (int c = tid; c < D_MODEL; c += 256) {
            int h = c >> 6;
            accO[c] = accO[c] * alpha_h[h] + p_h[h] * vt[c];
        }
        __syncthreads();
    }
    for (int c = tid; c < D_MODEL; c += 256) {
        int h = c >> 6, j = c & 63;
        out[(((size_t)(b * NUM_HEADS + h)) * SEQ + s) * D_K + j] = accO[c] / l_h[h];
    }
}

extern "C" void kernel_launch(void* const* d_in, const int* in_sizes, int n_in,
                              void* d_out, int out_size, void* d_ws, size_t ws_size,
                              hipStream_t stream) {
    const float* x  = (const float*)d_in[0];
    const float* Wq = (const float*)d_in[1];
    const float* bq = (const float*)d_in[2];
    const float* Wk = (const float*)d_in[3];
    const float* bk = (const float*)d_in[4];
    const float* Wv = (const float*)d_in[5];
    const float* bv = (const float*)d_in[6];
    float* out = (float*)d_out;

    const int nrows = BATCH * SEQ;  // 4096

    // workspace layout: inv_norm (16 KB) | v (16.8 MB) | mask (8.4 MB)
    float* inv_norm = (float*)d_ws;
    float* v = inv_norm + nrows;
    uint8_t* mask = (uint8_t*)(v + (size_t)nrows * D_MODEL);

    k_inv_norm<<<nrows / 4, 256, 0, stream>>>(x, inv_norm, nrows);

    dim3 gv(D_MODEL / TS, nrows / TS);  // (16, 64)
    k_gemm_nt_bias<<<gv, 256, 0, stream>>>(x, Wv, bv, v, nrows, D_MODEL, D_MODEL);

    dim3 gs(SEQ / TS, SEQ / TS, BATCH);  // (32, 32, 2)
    k_sim_mask<<<gs, 256, 0, stream>>>(x, inv_norm, mask);

    dim3 ga(SEQ, BATCH);
    k_attention<<<ga, 256, 0, stream>>>(x, Wq, bq, Wk, bk, v, mask, out);
}

// Round 2
// 141.554 us; speedup vs baseline: 4.0045x; 4.0045x over previous
//
#include <hip/hip_runtime.h>
#include <stdint.h>
#include <math.h>

#define D_MODEL 1024
#define NUM_HEADS 16
#define D_K 64
#define SEQ 2048
#define BATCH 2
#define SIM_THRESH 0.7f

#define BM 128
#define BN 128
#define BK 32

typedef __attribute__((ext_vector_type(8))) short bf16x8;
typedef __attribute__((ext_vector_type(4))) float f32x4;

static __device__ __forceinline__ unsigned short f2bf(float f) {
    unsigned int u = __float_as_uint(f);
    unsigned int r = (u + 0x7FFF + ((u >> 16) & 1)) >> 16;   // RNE
    return (unsigned short)r;
}
static __device__ __forceinline__ float bf2f(unsigned short u) {
    return __uint_as_float(((unsigned int)u) << 16);
}

// ---------- Kernel 1: normalize rows of x -> bf16, store norms, zero cnt ----------
__global__ __launch_bounds__(256) void k_prep(const float* __restrict__ x,
                                              unsigned short* __restrict__ xn,
                                              float* __restrict__ norms,
                                              int* __restrict__ cnt) {
    int row = blockIdx.x, tid = threadIdx.x;
    const float4* xr = (const float4*)(x + (size_t)row * D_MODEL);
    float4 vv = xr[tid];
    float ss = vv.x * vv.x + vv.y * vv.y + vv.z * vv.z + vv.w * vv.w;
    for (int off = 32; off > 0; off >>= 1) ss += __shfl_down(ss, off, 64);
    __shared__ float wsum[4];
    int lane = tid & 63, wv = tid >> 6;
    if (lane == 0) wsum[wv] = ss;
    __syncthreads();
    float tot = wsum[0] + wsum[1] + wsum[2] + wsum[3];
    float nrm = sqrtf(tot);
    float inv = 1.0f / fmaxf(nrm, 1e-12f);
    ushort4 o;
    o.x = f2bf(vv.x * inv); o.y = f2bf(vv.y * inv);
    o.z = f2bf(vv.z * inv); o.w = f2bf(vv.w * inv);
    *(ushort4*)(xn + (size_t)row * D_MODEL + tid * 4) = o;
    if (tid == 0) { norms[row] = nrm; cnt[row] = 0; }
}

// ---------- Kernel 2: cast Wv -> bf16 ----------
__global__ __launch_bounds__(256) void k_castW(const float* __restrict__ W,
                                               unsigned short* __restrict__ Wb) {
    size_t i = (size_t)blockIdx.x * 256 + threadIdx.x;   // 1M/4 float4 chunks
    float4 w = ((const float4*)W)[i];
    ushort4 o;
    o.x = f2bf(w.x); o.y = f2bf(w.y); o.z = f2bf(w.z); o.w = f2bf(w.w);
    *(ushort4*)(Wb + i * 4) = o;
}

// ---------- shared staging helper: 128x32 bf16 tile, global -> LDS, 16B/lane ----------
static __device__ __forceinline__ void stage_tile(const unsigned short* __restrict__ gsrc,
                                                  int ldk, int rowBase, int kk,
                                                  short* ldsDst, int tid) {
#pragma unroll
    for (int p = 0; p < 2; ++p) {
        int idx = p * 256 + tid;        // 0..511 chunks of 16B
        int row = idx >> 2;             // 0..127
        int ch  = idx & 3;              // 0..3
        const unsigned short* ga = gsrc + (size_t)(rowBase + row) * ldk + kk + ch * 8;
        __builtin_amdgcn_global_load_lds(
            (const __attribute__((address_space(1))) unsigned int*)ga,
            (__attribute__((address_space(3))) unsigned int*)(ldsDst + idx * 8),
            16, 0, 0);
    }
}

// ---------- Kernel 3: V projection  v[m,n] = norm[m]*sum_k xn[m,k]*Wvb[n,k] + bias[n] ----------
__global__ __launch_bounds__(256) void k_vproj(const unsigned short* __restrict__ xn,
                                               const unsigned short* __restrict__ Wvb,
                                               const float* __restrict__ bias,
                                               const float* __restrict__ norms,
                                               float* __restrict__ v) {
    __shared__ short lds[BM * BK + BN * BK];
    short* As = lds;
    short* Bs = lds + BM * BK;
    int tid = threadIdx.x;
    int lane = tid & 63, wave = tid >> 6;
    int wm = wave & 1, wn = wave >> 1;
    int lrow = lane & 15, quad = lane >> 4;
    int rowBase = blockIdx.y * BM;
    int colBase = blockIdx.x * BN;

    int aoff[4], boff[4];
#pragma unroll
    for (int i = 0; i < 4; ++i) {
        aoff[i] = (wm * 64 + i * 16 + lrow) * BK + quad * 8;
        boff[i] = (wn * 64 + i * 16 + lrow) * BK + quad * 8;
    }
    f32x4 acc[4][4] = {};
    for (int kk = 0; kk < D_MODEL; kk += BK) {
        stage_tile(xn, D_MODEL, rowBase, kk, As, tid);
        stage_tile(Wvb, D_MODEL, colBase, kk, Bs, tid);
        __syncthreads();
        bf16x8 av[4], bv[4];
#pragma unroll
        for (int i = 0; i < 4; ++i) av[i] = *(const bf16x8*)(As + aoff[i]);
#pragma unroll
        for (int i = 0; i < 4; ++i) bv[i] = *(const bf16x8*)(Bs + boff[i]);
#pragma unroll
        for (int mt = 0; mt < 4; ++mt)
#pragma unroll
            for (int nt = 0; nt < 4; ++nt)
                acc[mt][nt] = __builtin_amdgcn_mfma_f32_16x16x32_bf16(av[mt], bv[nt], acc[mt][nt], 0, 0, 0);
        __syncthreads();
    }
#pragma unroll
    for (int mt = 0; mt < 4; ++mt) {
#pragma unroll
        for (int nt = 0; nt < 4; ++nt) {
            int n = colBase + wn * 64 + nt * 16 + lrow;
            float bn = bias[n];
#pragma unroll
            for (int r = 0; r < 4; ++r) {
                int m = rowBase + wm * 64 + mt * 16 + quad * 4 + r;
                v[(size_t)m * D_MODEL + n] = acc[mt][nt][r] * norms[m] + bn;
            }
        }
    }
}

// ---------- Kernel 4: sim GEMM (xn . xn^T per batch), count mask bits per row ----------
__global__ __launch_bounds__(256) void k_sim(const unsigned short* __restrict__ xn,
                                             int* __restrict__ cnt) {
    __shared__ short lds[BM * BK + BN * BK];
    short* As = lds;
    short* Bs = lds + BM * BK;
    int b = blockIdx.z;
    const unsigned short* A = xn + (size_t)b * SEQ * D_MODEL;
    int tid = threadIdx.x;
    int lane = tid & 63, wave = tid >> 6;
    int wm = wave & 1, wn = wave >> 1;
    int lrow = lane & 15, quad = lane >> 4;
    int rowBase = blockIdx.y * BM;
    int colBase = blockIdx.x * BN;

    int aoff[4], boff[4];
#pragma unroll
    for (int i = 0; i < 4; ++i) {
        aoff[i] = (wm * 64 + i * 16 + lrow) * BK + quad * 8;
        boff[i] = (wn * 64 + i * 16 + lrow) * BK + quad * 8;
    }
    f32x4 acc[4][4] = {};
    for (int kk = 0; kk < D_MODEL; kk += BK) {
        stage_tile(A, D_MODEL, rowBase, kk, As, tid);
        stage_tile(A, D_MODEL, colBase, kk, Bs, tid);
        __syncthreads();
        bf16x8 av[4], bv[4];
#pragma unroll
        for (int i = 0; i < 4; ++i) av[i] = *(const bf16x8*)(As + aoff[i]);
#pragma unroll
        for (int i = 0; i < 4; ++i) bv[i] = *(const bf16x8*)(Bs + boff[i]);
#pragma unroll
        for (int mt = 0; mt < 4; ++mt)
#pragma unroll
            for (int nt = 0; nt < 4; ++nt)
                acc[mt][nt] = __builtin_amdgcn_mfma_f32_16x16x32_bf16(av[mt], bv[nt], acc[mt][nt], 0, 0, 0);
        __syncthreads();
    }
    int* cb = cnt + b * SEQ;
#pragma unroll
    for (int mt = 0; mt < 4; ++mt) {
#pragma unroll
        for (int nt = 0; nt < 4; ++nt) {
#pragma unroll
            for (int r = 0; r < 4; ++r) {
                int m = rowBase + wm * 64 + mt * 16 + quad * 4 + r;
                if (acc[mt][nt][r] > SIM_THRESH) atomicAdd(&cb[m], 1);
            }
        }
    }
}

// ---------- Kernel 5: attention. cnt==1 => only the diagonal is unmasked => out = v[s]. ----------
__global__ __launch_bounds__(256) void k_attn(
    const float* __restrict__ x,
    const float* __restrict__ Wq, const float* __restrict__ bq,
    const float* __restrict__ Wk, const float* __restrict__ bk,
    const float* __restrict__ v,
    const unsigned short* __restrict__ xn,
    const int* __restrict__ cnt,
    float* __restrict__ out)
{
    int s = blockIdx.x;
    int b = blockIdx.y;
    int tid = threadIdx.x;

    if (cnt[b * SEQ + s] == 1) {
        // softmax over a single finite score is exactly 1 -> copy v row
        const float4* vr = (const float4*)(v + ((size_t)b * SEQ + s) * D_MODEL);
        float4 val = vr[tid];
        int c = tid * 4;
        int h = c >> 6, j = c & 63;
        *(float4*)(out + (((size_t)(b * NUM_HEADS + h)) * SEQ + s) * D_K + j) = val;
        return;
    }

    // ---------- general path (cold): recompute mask row, online softmax ----------
    __shared__ uint8_t mrow[SEQ];
    const unsigned short* xs = xn + ((size_t)b * SEQ + s) * D_MODEL;
    for (int t = tid; t < SEQ; t += 256) {
        const unsigned short* xt = xn + ((size_t)b * SEQ + t) * D_MODEL;
        float d = 0.f;
        for (int k = 0; k < D_MODEL; ++k) d += bf2f(xs[k]) * bf2f(xt[k]);
        mrow[t] = (d > SIM_THRESH) ? 1 : 0;
    }
    __syncthreads();

    __shared__ float q_row[D_MODEL];
    __shared__ float k_row[D_MODEL];
    __shared__ float accO[D_MODEL];
    __shared__ float m_h[NUM_HEADS], l_h[NUM_HEADS], alpha_h[NUM_HEADS], p_h[NUM_HEADS];

    const float* xrow = x + ((size_t)b * SEQ + s) * D_MODEL;
    for (int c = tid; c < D_MODEL; c += 256) {
        const float* w = Wq + (size_t)c * D_MODEL;
        float acc = bq[c];
        for (int d = 0; d < D_MODEL; ++d) acc += xrow[d] * w[d];
        q_row[c] = acc;
        accO[c] = 0.f;
    }
    if (tid < NUM_HEADS) { m_h[tid] = -INFINITY; l_h[tid] = 0.f; }
    __syncthreads();

    for (int t = 0; t < SEQ; ++t) {
        if (!mrow[t]) continue;
        const float* xt = x + ((size_t)b * SEQ + t) * D_MODEL;
        for (int c = tid; c < D_MODEL; c += 256) {
            const float* w = Wk + (size_t)c * D_MODEL;
            float acc = bk[c];
            for (int d = 0; d < D_MODEL; ++d) acc += xt[d] * w[d];
            k_row[c] = acc;
        }
        __syncthreads();
        if (tid < NUM_HEADS) {
            float sc = 0.f;
            for (int j = 0; j < D_K; ++j) sc += q_row[tid * D_K + j] * k_row[tid * D_K + j];
            sc *= 0.125f;
            float mnew = fmaxf(m_h[tid], sc);
            float alpha = expf(m_h[tid] - mnew);
            float p = expf(sc - mnew);
            l_h[tid] = l_h[tid] * alpha + p;
            m_h[tid] = mnew;
            alpha_h[tid] = alpha;
            p_h[tid] = p;
        }
        __syncthreads();
        const float* vt = v + ((size_t)b * SEQ + t) * D_MODEL;
        for (int c = tid; c < D_MODEL; c += 256) {
            int h = c >> 6;
            accO[c] = accO[c] * alpha_h[h] + p_h[h] * vt[c];
        }
        __syncthreads();
    }
    for (int c = tid; c < D_MODEL; c += 256) {
        int h = c >> 6, j = c & 63;
        out[(((size_t)(b * NUM_HEADS + h)) * SEQ + s) * D_K + j] = accO[c] / l_h[h];
    }
}

extern "C" void kernel_launch(void* const* d_in, const int* in_sizes, int n_in,
                              void* d_out, int out_size, void* d_ws, size_t ws_size,
                              hipStream_t stream) {
    const float* x  = (const float*)d_in[0];
    const float* Wq = (const float*)d_in[1];
    const float* bq = (const float*)d_in[2];
    const float* Wk = (const float*)d_in[3];
    const float* bk = (const float*)d_in[4];
    const float* Wv = (const float*)d_in[5];
    const float* bv = (const float*)d_in[6];
    float* out = (float*)d_out;

    const int nrows = BATCH * SEQ;  // 4096

    // workspace: xn bf16 (8MB) | Wvb bf16 (2MB) | v fp32 (16MB) | norms (16KB) | cnt (16KB)
    unsigned short* xn  = (unsigned short*)d_ws;
    unsigned short* Wvb = xn + (size_t)nrows * D_MODEL;
    float* v     = (float*)(Wvb + (size_t)D_MODEL * D_MODEL);
    float* norms = v + (size_t)nrows * D_MODEL;
    int* cnt     = (int*)(norms + nrows);

    k_prep<<<nrows, 256, 0, stream>>>(x, xn, norms, cnt);
    k_castW<<<D_MODEL * D_MODEL / 1024, 256, 0, stream>>>(Wv, Wvb);

    dim3 gv(D_MODEL / BN, nrows / BM);           // (8, 32)
    k_vproj<<<gv, 256, 0, stream>>>(xn, Wvb, bv, norms, v);

    dim3 gs(SEQ / BN, SEQ / BM, BATCH);          // (16, 16, 2)
    k_sim<<<gs, 256, 0, stream>>>(xn, cnt);

    dim3 ga(SEQ, BATCH);
    k_attn<<<ga, 256, 0, stream>>>(x, Wq, bq, Wk, bk, v, xn, cnt, out);
}

// Round 3
// 130.849 us; speedup vs baseline: 4.3321x; 1.0818x over previous
//
#include <hip/hip_runtime.h>
#include <stdint.h>
#include <math.h>

#define D_MODEL 1024
#define NUM_HEADS 16
#define D_K 64
#define SEQ 2048
#define BATCH 2
#define SIM_THRESH 0.7f

#define BM 128
#define BN 128
#define BK 32

#define NROWS (BATCH * SEQ)              // 4096
#define VP_BLOCKS ((NROWS / BM) * (D_MODEL / BN))   // 32*8 = 256
#define SIM_TRI 136                      // 16*17/2 upper-triangle 128x128 blocks per batch
#define SIM_BLOCKS (SIM_TRI * BATCH)     // 272

typedef __attribute__((ext_vector_type(8))) short bf16x8;
typedef __attribute__((ext_vector_type(4))) float f32x4;

static __device__ __forceinline__ unsigned short f2bf(float f) {
    unsigned int u = __float_as_uint(f);
    unsigned int r = (u + 0x7FFF + ((u >> 16) & 1)) >> 16;   // RNE
    return (unsigned short)r;
}
static __device__ __forceinline__ float bf2f(unsigned short u) {
    return __uint_as_float(((unsigned int)u) << 16);
}

// ---------- L1: normalize x rows -> bf16 (+norms, zero cnt)  AND  cast Wv -> bf16 ----------
__global__ __launch_bounds__(256) void k_prep(const float* __restrict__ x,
                                              const float* __restrict__ Wv,
                                              unsigned short* __restrict__ xn,
                                              unsigned short* __restrict__ Wvb,
                                              float* __restrict__ norms,
                                              int* __restrict__ cnt) {
    int bid = blockIdx.x, tid = threadIdx.x;
    if (bid < NROWS) {
        const float4* xr = (const float4*)(x + (size_t)bid * D_MODEL);
        float4 vv = xr[tid];
        float ss = vv.x * vv.x + vv.y * vv.y + vv.z * vv.z + vv.w * vv.w;
        for (int off = 32; off > 0; off >>= 1) ss += __shfl_down(ss, off, 64);
        __shared__ float wsum[4];
        int lane = tid & 63, wv = tid >> 6;
        if (lane == 0) wsum[wv] = ss;
        __syncthreads();
        float nrm = sqrtf(wsum[0] + wsum[1] + wsum[2] + wsum[3]);
        float inv = 1.0f / fmaxf(nrm, 1e-12f);
        ushort4 o;
        o.x = f2bf(vv.x * inv); o.y = f2bf(vv.y * inv);
        o.z = f2bf(vv.z * inv); o.w = f2bf(vv.w * inv);
        *(ushort4*)(xn + (size_t)bid * D_MODEL + tid * 4) = o;
        if (tid == 0) { norms[bid] = nrm; cnt[bid] = 0; }
    } else {
        size_t i = (size_t)(bid - NROWS) * 256 + tid;   // float4 chunk index
        float4 w = ((const float4*)Wv)[i];
        ushort4 o;
        o.x = f2bf(w.x); o.y = f2bf(w.y); o.z = f2bf(w.z); o.w = f2bf(w.w);
        *(ushort4*)(Wvb + i * 4) = o;
    }
}

// ---------- staging: 128x32 bf16 tile global -> LDS, 16B/lane ----------
static __device__ __forceinline__ void stage_tile(const unsigned short* __restrict__ gsrc,
                                                  int rowBase, int kk,
                                                  short* ldsDst, int tid) {
#pragma unroll
    for (int p = 0; p < 2; ++p) {
        int idx = p * 256 + tid;        // 0..511 chunks of 16B
        int row = idx >> 2;             // 0..127
        int ch  = idx & 3;              // 0..3
        const unsigned short* ga = gsrc + (size_t)(rowBase + row) * D_MODEL + kk + ch * 8;
        __builtin_amdgcn_global_load_lds(
            (const __attribute__((address_space(1))) unsigned int*)ga,
            (__attribute__((address_space(3))) unsigned int*)(ldsDst + idx * 8),
            16, 0, 0);
    }
}

// ---------- L2: fused V-projection (blocks 0..255) + symmetric sim/count (blocks 256..527) ----------
// vproj: v[m,n] = norm[m]*sum_k xn[m,k]*Wvb[n,k] + bv[n]; also written straight to out
//        (valid final answer for singleton-mask rows; fix pass repairs the rest).
// sim:   upper-triangle 128x128 blocks of xn.xn^T per batch; count entries > thresh into
//        cnt[m] (and cnt[n] for off-diagonal blocks, by symmetry).
__global__ __launch_bounds__(256) void k_main(const unsigned short* __restrict__ xn,
                                              const unsigned short* __restrict__ Wvb,
                                              const float* __restrict__ bv,
                                              const float* __restrict__ norms,
                                              float* __restrict__ v,
                                              int* __restrict__ cnt,
                                              float* __restrict__ out) {
    __shared__ short As[BM * BK];
    __shared__ short Bs[BN * BK];
    int bid = blockIdx.x;
    int tid = threadIdx.x;
    int lane = tid & 63, wave = tid >> 6;
    int wm = wave & 1, wn = wave >> 1;
    int lrow = lane & 15, quad = lane >> 4;

    const unsigned short* Asrc;
    const unsigned short* Bsrc;
    int rowBase, colBase;
    bool isV;
    int b = 0, bi = 0, bj = 0;
    if (bid < VP_BLOCKS) {
        isV = true;
        rowBase = (bid >> 3) * BM;      // global row block (0..31)
        colBase = (bid & 7) * BN;       // col block (0..7)
        Asrc = xn;
        Bsrc = Wvb;
    } else {
        isV = false;
        int sidx = bid - VP_BLOCKS;
        b = (sidx >= SIM_TRI) ? 1 : 0;
        int idx = sidx - b * SIM_TRI;
        int r = idx;
        bi = 0;
        while (r >= 16 - bi) { r -= 16 - bi; ++bi; }
        bj = bi + r;
        rowBase = bi * BM;              // batch-local
        colBase = bj * BN;
        Asrc = xn + (size_t)b * SEQ * D_MODEL;
        Bsrc = Asrc;
    }

    int aoff[4], boff[4];
#pragma unroll
    for (int i = 0; i < 4; ++i) {
        aoff[i] = (wm * 64 + i * 16 + lrow) * BK + quad * 8;
        boff[i] = (wn * 64 + i * 16 + lrow) * BK + quad * 8;
    }
    f32x4 acc[4][4] = {};
    for (int kk = 0; kk < D_MODEL; kk += BK) {
        stage_tile(Asrc, rowBase, kk, As, tid);
        stage_tile(Bsrc, colBase, kk, Bs, tid);
        __syncthreads();
        bf16x8 av[4], bvv[4];
#pragma unroll
        for (int i = 0; i < 4; ++i) av[i] = *(const bf16x8*)(As + aoff[i]);
#pragma unroll
        for (int i = 0; i < 4; ++i) bvv[i] = *(const bf16x8*)(Bs + boff[i]);
#pragma unroll
        for (int mt = 0; mt < 4; ++mt)
#pragma unroll
            for (int nt = 0; nt < 4; ++nt)
                acc[mt][nt] = __builtin_amdgcn_mfma_f32_16x16x32_bf16(av[mt], bvv[nt], acc[mt][nt], 0, 0, 0);
        __syncthreads();
    }

    if (isV) {
#pragma unroll
        for (int mt = 0; mt < 4; ++mt) {
#pragma unroll
            for (int nt = 0; nt < 4; ++nt) {
                int n = colBase + wn * 64 + nt * 16 + lrow;
                float bn = bv[n];
                int h = n >> 6, j = n & 63;
#pragma unroll
                for (int r = 0; r < 4; ++r) {
                    int m = rowBase + wm * 64 + mt * 16 + quad * 4 + r;
                    float val = acc[mt][nt][r] * norms[m] + bn;
                    v[(size_t)m * D_MODEL + n] = val;
                    int bb = m >> 11, s = m & (SEQ - 1);
                    out[(((size_t)(bb * NUM_HEADS + h)) * SEQ + s) * D_K + j] = val;
                }
            }
        }
    } else {
        int* cb = cnt + b * SEQ;
        bool diag = (bi == bj);
#pragma unroll
        for (int mt = 0; mt < 4; ++mt) {
#pragma unroll
            for (int nt = 0; nt < 4; ++nt) {
                int n = colBase + wn * 64 + nt * 16 + lrow;
#pragma unroll
                for (int r = 0; r < 4; ++r) {
                    int m = rowBase + wm * 64 + mt * 16 + quad * 4 + r;
                    if (acc[mt][nt][r] > SIM_THRESH) {
                        atomicAdd(&cb[m], 1);
                        if (!diag) atomicAdd(&cb[n], 1);
                    }
                }
            }
        }
    }
}

// ---------- L3: fix pass. Rows with cnt==1 already hold the right answer (out = v row).
// Rows with cnt!=1 (cold) get the full online-softmax fallback. ----------
__global__ __launch_bounds__(256) void k_fix(
    const float* __restrict__ x,
    const float* __restrict__ Wq, const float* __restrict__ bq,
    const float* __restrict__ Wk, const float* __restrict__ bk,
    const float* __restrict__ v,
    const unsigned short* __restrict__ xn,
    const int* __restrict__ cnt,
    float* __restrict__ out)
{
    int tid = threadIdx.x;
    int rowBase = blockIdx.x * 256;

    __shared__ int list[256];
    __shared__ int nlist;
    if (tid == 0) nlist = 0;
    __syncthreads();
    int grow = rowBase + tid;
    if (cnt[grow] != 1) { int p = atomicAdd(&nlist, 1); list[p] = grow; }
    __syncthreads();
    int nfix = nlist;
    if (nfix == 0) return;

    __shared__ uint8_t mrow[SEQ];
    __shared__ float q_row[D_MODEL];
    __shared__ float k_row[D_MODEL];
    __shared__ float accO[D_MODEL];
    __shared__ float m_h[NUM_HEADS], l_h[NUM_HEADS], alpha_h[NUM_HEADS], p_h[NUM_HEADS];

    for (int li = 0; li < nfix; ++li) {
        int row = list[li];
        int b = row >> 11, s = row & (SEQ - 1);

        const unsigned short* xs = xn + (size_t)row * D_MODEL;
        for (int t = tid; t < SEQ; t += 256) {
            const unsigned short* xt = xn + ((size_t)b * SEQ + t) * D_MODEL;
            float d = 0.f;
            for (int k = 0; k < D_MODEL; ++k) d += bf2f(xs[k]) * bf2f(xt[k]);
            mrow[t] = (d > SIM_THRESH) ? 1 : 0;
        }

        const float* xrow = x + (size_t)row * D_MODEL;
        for (int c = tid; c < D_MODEL; c += 256) {
            const float* w = Wq + (size_t)c * D_MODEL;
            float acc = bq[c];
            for (int d = 0; d < D_MODEL; ++d) acc += xrow[d] * w[d];
            q_row[c] = acc;
            accO[c] = 0.f;
        }
        if (tid < NUM_HEADS) { m_h[tid] = -INFINITY; l_h[tid] = 0.f; }
        __syncthreads();

        for (int t = 0; t < SEQ; ++t) {
            if (!mrow[t]) continue;
            const float* xt = x + ((size_t)b * SEQ + t) * D_MODEL;
            for (int c = tid; c < D_MODEL; c += 256) {
                const float* w = Wk + (size_t)c * D_MODEL;
                float acc = bk[c];
                for (int d = 0; d < D_MODEL; ++d) acc += xt[d] * w[d];
                k_row[c] = acc;
            }
            __syncthreads();
            if (tid < NUM_HEADS) {
                float sc = 0.f;
                for (int j = 0; j < D_K; ++j) sc += q_row[tid * D_K + j] * k_row[tid * D_K + j];
                sc *= 0.125f;
                float mnew = fmaxf(m_h[tid], sc);
                float alpha = expf(m_h[tid] - mnew);
                float p = expf(sc - mnew);
                l_h[tid] = l_h[tid] * alpha + p;
                m_h[tid] = mnew;
                alpha_h[tid] = alpha;
                p_h[tid] = p;
            }
            __syncthreads();
            const float* vt = v + ((size_t)b * SEQ + t) * D_MODEL;
            for (int c = tid; c < D_MODEL; c += 256) {
                int h = c >> 6;
                accO[c] = accO[c] * alpha_h[h] + p_h[h] * vt[c];
            }
            __syncthreads();
        }
        for (int c = tid; c < D_MODEL; c += 256) {
            int h = c >> 6, j = c & 63;
            out[(((size_t)(b * NUM_HEADS + h)) * SEQ + s) * D_K + j] = accO[c] / l_h[h];
        }
        __syncthreads();
    }
}

extern "C" void kernel_launch(void* const* d_in, const int* in_sizes, int n_in,
                              void* d_out, int out_size, void* d_ws, size_t ws_size,
                              hipStream_t stream) {
    const float* x  = (const float*)d_in[0];
    const float* Wq = (const float*)d_in[1];
    const float* bq = (const float*)d_in[2];
    const float* Wk = (const float*)d_in[3];
    const float* bk = (const float*)d_in[4];
    const float* Wv = (const float*)d_in[5];
    const float* bv = (const float*)d_in[6];
    float* out = (float*)d_out;

    // workspace: xn bf16 (8MB) | Wvb bf16 (2MB) | v fp32 (16MB) | norms (16KB) | cnt (16KB)
    unsigned short* xn  = (unsigned short*)d_ws;
    unsigned short* Wvb = xn + (size_t)NROWS * D_MODEL;
    float* v     = (float*)(Wvb + (size_t)D_MODEL * D_MODEL);
    float* norms = v + (size_t)NROWS * D_MODEL;
    int* cnt     = (int*)(norms + NROWS);

    // L1: 4096 row-normalize blocks + 1024 Wv-cast blocks
    k_prep<<<NROWS + D_MODEL * D_MODEL / 1024, 256, 0, stream>>>(x, Wv, xn, Wvb, norms, cnt);

    // L2: 256 vproj blocks + 272 sim blocks
    k_main<<<VP_BLOCKS + SIM_BLOCKS, 256, 0, stream>>>(xn, Wvb, bv, norms, v, cnt, out);

    // L3: fix non-singleton rows (cold)
    k_fix<<<NROWS / 256, 256, 0, stream>>>(x, Wq, bq, Wk, bk, v, xn, cnt, out);
}